// Round 5
// baseline (246.773 us; speedup 1.0000x reference)
//
#include <hip/hip_runtime.h>

// SpectralMultiHeadAttention on MI355X (gfx950)
// b=4, hw=16384, c=256, heads=8, dh=32.
// S[b] = x^T x;  SW = S@[Wq|Wk];  G_h = Wq_h^T SWk_h;  diag norms from SW;
// A = softmax;  U = A^T-weighted Wout;  W3 = Wv@U;  out = x @ W3.
// R5: fix k_out staging under-fill (e<4 -> e<8; rows 64..127 were never
// written -> NaN from uninitialized LDS). Structure unchanged from R4.

#define B_   4
#define HW_  16384
#define C_   256

typedef __attribute__((ext_vector_type(8))) short short8;
typedef __attribute__((ext_vector_type(4))) float floatx4;

__device__ __forceinline__ unsigned short f2bf(float f) {
  unsigned u = __builtin_bit_cast(unsigned, f);
  u += 0x7FFFu + ((u >> 16) & 1u);          // round-to-nearest-even
  return (unsigned short)(u >> 16);
}

__device__ __forceinline__ void gl_lds16(const unsigned short* g, unsigned short* l) {
  __builtin_amdgcn_global_load_lds(
      (const __attribute__((address_space(1))) unsigned int*)g,
      (__attribute__((address_space(3))) unsigned int*)l, 16, 0, 0);
}

// ---------------------------------------------------------------------------
// K1: cast fp32 -> bf16 transpose only: xT [b][c][hw]. grid 4096, 256 thr.
// ---------------------------------------------------------------------------
__global__ __launch_bounds__(256) void k_cast_t(const float* __restrict__ x,
                                                unsigned short* __restrict__ xT) {
  __shared__ unsigned short lds[64][72];
  int bid = blockIdx.x;
  int t = threadIdx.x;
  int ct = bid & 3;
  int pt = (bid >> 2) & 255;
  int b  = bid >> 10;
  const float* src = x + ((size_t)(b * HW_ + pt * 64)) * C_ + ct * 64;
#pragma unroll
  for (int e = 0; e < 4; e++) {
    int lin = t + e * 256;          // (p, c4)
    int p = lin >> 4, c4 = lin & 15;
    float4 v = *(const float4*)(src + (size_t)p * C_ + c4 * 4);
    lds[c4 * 4 + 0][p] = f2bf(v.x);
    lds[c4 * 4 + 1][p] = f2bf(v.y);
    lds[c4 * 4 + 2][p] = f2bf(v.z);
    lds[c4 * 4 + 3][p] = f2bf(v.w);
  }
  __syncthreads();
#pragma unroll
  for (int e = 0; e < 4; e++) {
    int lin = t + e * 256;          // (c, p4)
    int c = lin >> 4, p4 = lin & 15;
    ushort4 h;
    h.x = lds[c][p4 * 4 + 0];
    h.y = lds[c][p4 * 4 + 1];
    h.z = lds[c][p4 * 4 + 2];
    h.w = lds[c][p4 * 4 + 3];
    *(ushort4*)(xT + ((size_t)(b * C_ + ct * 64 + c)) * HW_ + pt * 64 + p4 * 4) = h;
  }
}

// ---------------------------------------------------------------------------
// K2: S partials. grid 256 = b(4)*mt(2)*nt(2)*ks(16). Each block: 128x128 tile
// over K-chunk 1024 as 4 phases of BK=256 (128 KiB LDS, xor-32 swizzle,
// global_load_lds width-16).
// ---------------------------------------------------------------------------
__global__ __launch_bounds__(256) void k_sgemm(const unsigned short* __restrict__ xT,
                                               float* __restrict__ part) {
  __shared__ unsigned short At[128 * 256];   // 64 KiB
  __shared__ unsigned short Bt[128 * 256];   // 64 KiB
  int bid = blockIdx.x;
  int ks = bid & 15, nt = (bid >> 4) & 1, mt = (bid >> 5) & 1, b = bid >> 6;
  const unsigned short* Ab = xT + ((size_t)(b * C_ + mt * 128)) * HW_ + ks * 1024;
  const unsigned short* Bb = xT + ((size_t)(b * C_ + nt * 128)) * HW_ + ks * 1024;
  int t = threadIdx.x, lane = t & 63, w = t >> 6;
  int wm = w >> 1, wn = w & 1;
  int l15 = lane & 15, l4 = lane >> 4;
  int lrow = lane >> 5;           // row within a 2-row issue
  int lslot = lane & 31;          // LDS octet slot this lane fills
  floatx4 acc[4][4];
  floatx4 z = {0.f, 0.f, 0.f, 0.f};
#pragma unroll
  for (int i = 0; i < 4; i++)
#pragma unroll
    for (int j = 0; j < 4; j++) acc[i][j] = z;

  for (int ph = 0; ph < 4; ph++) {
    if (ph) __syncthreads();
#pragma unroll
    for (int i = 0; i < 16; i++) {
      int issue = w * 16 + i;              // 0..63
      int row = issue * 2 + lrow;          // 0..127
      int goct = lslot ^ (row & 31);
      gl_lds16(Ab + (size_t)row * HW_ + ph * 256 + goct * 8, At + issue * 512);
      gl_lds16(Bb + (size_t)row * HW_ + ph * 256 + goct * 8, Bt + issue * 512);
    }
    __syncthreads();
#pragma unroll
    for (int kk = 0; kk < 8; kk++) {
      short8 af[4], bfv[4];
      int oct = kk * 4 + l4;
#pragma unroll
      for (int tm = 0; tm < 4; tm++) {
        int row = wm * 64 + tm * 16 + l15;
        af[tm] = *(const short8*)(At + row * 256 + ((oct ^ (row & 31)) * 8));
      }
#pragma unroll
      for (int tn = 0; tn < 4; tn++) {
        int row = wn * 64 + tn * 16 + l15;
        bfv[tn] = *(const short8*)(Bt + row * 256 + ((oct ^ (row & 31)) * 8));
      }
#pragma unroll
      for (int tm = 0; tm < 4; tm++)
#pragma unroll
        for (int tn = 0; tn < 4; tn++)
          acc[tm][tn] = __builtin_amdgcn_mfma_f32_16x16x32_bf16(af[tm], bfv[tn],
                                                                acc[tm][tn], 0, 0, 0);
    }
  }
  float* pb = part + (size_t)bid * 16384;
#pragma unroll
  for (int tm = 0; tm < 4; tm++)
#pragma unroll
    for (int tn = 0; tn < 4; tn++)
#pragma unroll
      for (int r = 0; r < 4; r++) {
        int m = wm * 64 + tm * 16 + l4 * 4 + r;   // C/D: row=(lane>>4)*4+reg
        int n = wn * 64 + tn * 16 + l15;          //      col=lane&15
        pb[m * 128 + n] = acc[tm][tn][r];
      }
}

// ---------------------------------------------------------------------------
// K3: fused partial-reduce + SW gemm. grid 128 = b(4)*ms(8)*ns(4).
// Block reduces its S-slice (rows ms*32..+32, all 256 cols) from 16 partials
// into LDS (transposed SsT[col][r]), then SW-slice = Sslice @ Wsel[:, 128 n]
// via fp32 4x4 microkernel. ns 0,1 -> SWq halves; 2,3 -> SWk halves.
// ---------------------------------------------------------------------------
__global__ __launch_bounds__(256) void k_sw(const float* __restrict__ part,
                                            const float* __restrict__ Wq,
                                            const float* __restrict__ Wk,
                                            float* __restrict__ SWq,
                                            float* __restrict__ SWk) {
  __shared__ float SsT[256][36];    // 36.9 KiB  S[ms*32+r][m] at [m][r]
  __shared__ float Ws[128][132];    // 67.6 KiB  W[strip*128+ml][n0+n]
  int bid = blockIdx.x;
  int ns = bid & 3, ms = (bid >> 2) & 7, b = bid >> 5;
  const float* Wsel = (ns < 2) ? Wq : Wk;
  float* SWsel = (ns < 2) ? SWq : SWk;
  int n0 = (ns & 1) * 128;
  int t = threadIdx.x;
  int nt_lane = t >> 7;             // which column-half of part tiles
  int cl = t & 127;
#pragma unroll 4
  for (int e = 0; e < 32; e++) {
    int R = ms * 32 + e;
    int mt = R >> 7;
    const float* p = part + ((size_t)(((b * 2 + mt) * 2 + nt_lane) * 16)) * 16384
                     + (R & 127) * 128 + cl;
    float s = 0.f;
#pragma unroll
    for (int k = 0; k < 16; k++) s += p[(size_t)k * 16384];
    SsT[t][e] = s;
  }
  int tx = t & 31, ty = t >> 5;
  float acc[4][4] = {};
  for (int strip = 0; strip < 2; strip++) {
    if (strip) __syncthreads();
#pragma unroll
    for (int e = 0; e < 16; e++) {
      int idx = e * 256 + t;
      int ml = idx >> 5, n4 = idx & 31;
      float4 v = *(const float4*)(Wsel + ((size_t)(strip * 128 + ml)) * C_ + n0 + n4 * 4);
      Ws[ml][n4 * 4 + 0] = v.x; Ws[ml][n4 * 4 + 1] = v.y;
      Ws[ml][n4 * 4 + 2] = v.z; Ws[ml][n4 * 4 + 3] = v.w;
    }
    __syncthreads();
#pragma unroll 8
    for (int ml = 0; ml < 128; ml++) {
      int m = strip * 128 + ml;
      float4 aq = *(const float4*)&SsT[m][ty * 4];
      float4 bq = *(const float4*)&Ws[ml][tx * 4];
      float av[4] = {aq.x, aq.y, aq.z, aq.w};
      float bv[4] = {bq.x, bq.y, bq.z, bq.w};
#pragma unroll
      for (int i = 0; i < 4; i++)
#pragma unroll
        for (int j = 0; j < 4; j++) acc[i][j] += av[i] * bv[j];
    }
  }
#pragma unroll
  for (int i = 0; i < 4; i++) {
    int row = ms * 32 + ty * 4 + i;
    float4 v = {acc[i][0], acc[i][1], acc[i][2], acc[i][3]};
    *(float4*)(SWsel + ((size_t)(b * C_ + row)) * C_ + n0 + tx * 4) = v;
  }
}

// ---------------------------------------------------------------------------
// K4: fused G_h + norms + softmax + U_h. grid 32 = (b,h), 256 thr.
// ---------------------------------------------------------------------------
__global__ __launch_bounds__(256) void k_fuse(const float* __restrict__ Wq,
                                              const float* __restrict__ Wk,
                                              const float* __restrict__ SWq,
                                              const float* __restrict__ SWk,
                                              const float* __restrict__ Wout,
                                              float* __restrict__ U) {
  __shared__ float Wqh[256][32];    // reused as Wo[32][256] for U phase
  __shared__ float Wkh[256][32];
  __shared__ float SWqh[256][32];
  __shared__ float SWkh[256][32];
  __shared__ float Lg[32][33];
  __shared__ float qp[8][32], kp[8][32], qin[32], kin[32];
  int b = blockIdx.x >> 3, h = blockIdx.x & 7;
  int t = threadIdx.x;
  int col = t & 31, rgrp = t >> 5;
  for (int r0 = 0; r0 < 256; r0 += 8) {
    int row = r0 + rgrp;
    Wqh[row][col]  = Wq[(size_t)row * C_ + h * 32 + col];
    Wkh[row][col]  = Wk[(size_t)row * C_ + h * 32 + col];
    SWqh[row][col] = SWq[((size_t)(b * C_ + row)) * C_ + h * 32 + col];
    SWkh[row][col] = SWk[((size_t)(b * C_ + row)) * C_ + h * 32 + col];
  }
  __syncthreads();
  {
    float g[4] = {0.f, 0.f, 0.f, 0.f};
    for (int k = 0; k < 256; k++) {
      float swk = SWkh[k][col];
#pragma unroll
      for (int r = 0; r < 4; r++) g[r] += Wqh[k][rgrp + 8 * r] * swk;
    }
#pragma unroll
    for (int r = 0; r < 4; r++) Lg[rgrp + 8 * r][col] = g[r];
  }
  {
    float sq = 0.f, sk = 0.f;
    for (int k = rgrp * 32; k < rgrp * 32 + 32; k++) {
      sq += Wqh[k][col] * SWqh[k][col];
      sk += Wkh[k][col] * SWkh[k][col];
    }
    qp[rgrp][col] = sq;
    kp[rgrp][col] = sk;
  }
  __syncthreads();
  if (t < 32) {
    float a = 0.f;
#pragma unroll
    for (int p = 0; p < 8; p++) a += qp[p][t];
    qin[t] = rsqrtf(a);
  } else if (t < 64) {
    int j = t - 32;
    float a = 0.f;
#pragma unroll
    for (int p = 0; p < 8; p++) a += kp[p][j];
    kin[j] = rsqrtf(a);
  }
  __syncthreads();
  if (t < 32) {
    float row[32];
    float mx = -1e30f;
#pragma unroll
    for (int j = 0; j < 32; j++) {
      row[j] = Lg[t][j] * qin[t] * kin[j] * 0.0078125f;   // /sqrt(16384)
      mx = fmaxf(mx, row[j]);
    }
    float sum = 0.f;
#pragma unroll
    for (int j = 0; j < 32; j++) { row[j] = __expf(row[j] - mx); sum += row[j]; }
    float inv = 1.0f / sum;
#pragma unroll
    for (int j = 0; j < 32; j++) Lg[t][j] = row[j] * inv;
  }
  __syncthreads();
  float (*Wo)[256] = reinterpret_cast<float(*)[256]>(&Wqh[0][0]);
#pragma unroll
  for (int r = 0; r < 32; r++) Wo[r][t] = Wout[((size_t)(h * 32 + r)) * C_ + t];
  __syncthreads();
  for (int j = 0; j < 32; j++) {
    float a = 0.f;
#pragma unroll
    for (int i2 = 0; i2 < 32; i2++) a += Lg[i2][j] * Wo[i2][t];
    U[((size_t)(b * C_ + h * 32 + j)) * C_ + t] = a;
  }
}

// ---------------------------------------------------------------------------
// K5: W3T = (Wv @ U[b])^T, fp32 [b][n][c]. grid 64.
// ---------------------------------------------------------------------------
__global__ __launch_bounds__(256) void k_gemm_w3(const float* __restrict__ Wv,
                                                 const float* __restrict__ U,
                                                 float* __restrict__ W3T) {
  __shared__ float As[64][17];
  __shared__ float Bs[16][65];
  int bid = blockIdx.x;
  int nt = bid & 3, mt = (bid >> 2) & 3, b = bid >> 4;
  int mb = mt * 64, nb = nt * 64;
  int t = threadIdx.x, tx = t & 15, ty = t >> 4;
  float acc[4][4] = {};
  for (int kt = 0; kt < 16; kt++) {
    {
      int row = t >> 2, kq = t & 3;
      float4 v = *(const float4*)(Wv + ((size_t)(mb + row)) * C_ + kt * 16 + kq * 4);
      As[row][kq * 4 + 0] = v.x; As[row][kq * 4 + 1] = v.y;
      As[row][kq * 4 + 2] = v.z; As[row][kq * 4 + 3] = v.w;
    }
    {
      int kk = t >> 4, n4 = t & 15;
      float4 v = *(const float4*)(U + ((size_t)(b * C_ + kt * 16 + kk)) * C_ + nb + n4 * 4);
      Bs[kk][n4 * 4 + 0] = v.x; Bs[kk][n4 * 4 + 1] = v.y;
      Bs[kk][n4 * 4 + 2] = v.z; Bs[kk][n4 * 4 + 3] = v.w;
    }
    __syncthreads();
#pragma unroll
    for (int k = 0; k < 16; k++) {
      float a[4], bb[4];
#pragma unroll
      for (int i = 0; i < 4; i++) a[i] = As[ty * 4 + i][k];
#pragma unroll
      for (int j = 0; j < 4; j++) bb[j] = Bs[k][tx * 4 + j];
#pragma unroll
      for (int i = 0; i < 4; i++)
#pragma unroll
        for (int j = 0; j < 4; j++) acc[i][j] += a[i] * bb[j];
    }
    __syncthreads();
  }
#pragma unroll
  for (int i = 0; i < 4; i++)
#pragma unroll
    for (int j = 0; j < 4; j++)
      W3T[((size_t)(b * C_ + nb + tx * 4 + j)) * C_ + mb + ty * 4 + i] = acc[i][j];
}

// ---------------------------------------------------------------------------
// K6: out = x @ W3[b]. grid 1024 = mtile(512)*ntile(2). A staged from x fp32
// (inline cvt->bf16), B from W3T fp32 likewise. 72-short LDS pitch.
// Staging: 128 rows x 16 quads = 2048 float4 items per operand -> e<8.
// ---------------------------------------------------------------------------
__global__ __launch_bounds__(256) void k_out(const float* __restrict__ x,
                                             const float* __restrict__ W3T,
                                             float* __restrict__ out) {
  __shared__ unsigned short At[128 * 72];   // 18 KiB
  __shared__ unsigned short Bt[128 * 72];   // 18 KiB
  int bid = blockIdx.x;
  int ntile = bid & 1, mtile = bid >> 1;
  int b = mtile >> 7;
  const float* Ab = x + (size_t)mtile * 128 * C_;
  const float* Bb = W3T + ((size_t)(b * C_ + ntile * 128)) * C_;
  int t = threadIdx.x, lane = t & 63, w = t >> 6;
  int wm = w >> 1, wn = w & 1;
  int l15 = lane & 15, l4 = lane >> 4;
  floatx4 acc[4][4];
  floatx4 z = {0.f, 0.f, 0.f, 0.f};
#pragma unroll
  for (int i = 0; i < 4; i++)
#pragma unroll
    for (int j = 0; j < 4; j++) acc[i][j] = z;
  for (int s = 0; s < 4; s++) {              // BK=64, K=256
    if (s) __syncthreads();
#pragma unroll
    for (int e = 0; e < 8; e++) {
      int idx = e * 256 + t;                 // 2048 = 128 rows x 16 quads
      int r = idx >> 4, c4 = idx & 15;
      float4 va = *(const float4*)(Ab + (size_t)r * C_ + s * 64 + c4 * 4);
      float4 vb = *(const float4*)(Bb + (size_t)r * C_ + s * 64 + c4 * 4);
      ushort4 ha, hb;
      ha.x = f2bf(va.x); ha.y = f2bf(va.y); ha.z = f2bf(va.z); ha.w = f2bf(va.w);
      hb.x = f2bf(vb.x); hb.y = f2bf(vb.y); hb.z = f2bf(vb.z); hb.w = f2bf(vb.w);
      *(ushort4*)(At + r * 72 + c4 * 4) = ha;
      *(ushort4*)(Bt + r * 72 + c4 * 4) = hb;
    }
    __syncthreads();
#pragma unroll
    for (int kk = 0; kk < 2; kk++) {
      short8 af[4], bfv[4];
      int oct = kk * 4 + l4;
#pragma unroll
      for (int tm = 0; tm < 4; tm++) {
        int row = wm * 64 + tm * 16 + l15;
        af[tm] = *(const short8*)(At + row * 72 + oct * 8);
      }
#pragma unroll
      for (int tn = 0; tn < 4; tn++) {
        int row = wn * 64 + tn * 16 + l15;
        bfv[tn] = *(const short8*)(Bt + row * 72 + oct * 8);
      }
#pragma unroll
      for (int tm = 0; tm < 4; tm++)
#pragma unroll
        for (int tn = 0; tn < 4; tn++)
          acc[tm][tn] = __builtin_amdgcn_mfma_f32_16x16x32_bf16(af[tm], bfv[tn],
                                                                acc[tm][tn], 0, 0, 0);
    }
  }
  float* ob = out + (size_t)mtile * 128 * C_ + ntile * 128;
#pragma unroll
  for (int tm = 0; tm < 4; tm++)
#pragma unroll
    for (int tn = 0; tn < 4; tn++)
#pragma unroll
      for (int r = 0; r < 4; r++) {
        int m = wm * 64 + tm * 16 + l4 * 4 + r;
        int n = wn * 64 + tn * 16 + l15;
        ob[(size_t)m * C_ + n] = acc[tm][tn][r];
      }
}

// ---------------------------------------------------------------------------
extern "C" void kernel_launch(void* const* d_in, const int* in_sizes, int n_in,
                              void* d_out, int out_size, void* d_ws, size_t ws_size,
                              hipStream_t stream) {
  const float* x    = (const float*)d_in[0];
  const float* Wq   = (const float*)d_in[1];
  const float* Wk   = (const float*)d_in[2];
  const float* Wv   = (const float*)d_in[3];
  const float* Wout = (const float*)d_in[4];
  float* out = (float*)d_out;

  // workspace carve-up (~52 MiB)
  unsigned short* xT = (unsigned short*)d_ws;          // 32 MiB
  float* part = (float*)(xT + (size_t)16777216);       // 256*16384 fp32 = 16 MiB
  float* SWq  = part + (size_t)4194304;                // 1 MiB
  float* SWk  = SWq + 262144;                          // 1 MiB
  float* U    = SWk + 262144;                          // 1 MiB
  float* W3T  = U + 262144;                            // 1 MiB

  k_cast_t<<<dim3(4096), dim3(256), 0, stream>>>(x, xT);
  k_sgemm<<<dim3(256), dim3(256), 0, stream>>>(xT, part);
  k_sw<<<dim3(128), dim3(256), 0, stream>>>(part, Wq, Wk, SWq, SWk);
  k_fuse<<<dim3(32), dim3(256), 0, stream>>>(Wq, Wk, SWq, SWk, Wout, U);
  k_gemm_w3<<<dim3(64), dim3(256), 0, stream>>>(Wv, U, W3T);
  k_out<<<dim3(1024), dim3(256), 0, stream>>>(x, W3T, out);
}